// Round 2
// baseline (6771.996 us; speedup 1.0000x reference)
//
#include <hip/hip_runtime.h>
#include <stdint.h>

typedef __attribute__((ext_vector_type(8))) short bf16x8;
typedef __attribute__((ext_vector_type(4))) float f32x4;
typedef __attribute__((ext_vector_type(4))) unsigned int u32x4;

__device__ __forceinline__ unsigned short f2bf(float f) {
  unsigned int u = __float_as_uint(f);
  return (unsigned short)((u + 0x7fffu + ((u >> 16) & 1u)) >> 16);  // RNE
}

__device__ __forceinline__ void gload16(const void* g, void* l) {
  __builtin_amdgcn_global_load_lds((const __attribute__((address_space(1))) void*)g,
                                   (__attribute__((address_space(3))) void*)l, 16, 0, 0);
}

// ---------------------------------------------------------------- zero
__global__ void zero_k(u32x4* __restrict__ p, int n16) {
  int i = blockIdx.x * blockDim.x + threadIdx.x;
  int stride = gridDim.x * blockDim.x;
  u32x4 z = {0u, 0u, 0u, 0u};
  for (; i < n16; i += stride) p[i] = z;
}

// ------------------------------------------- fp32 NHWC -> padded bf16 NHWC
// dst layout: [8][H+2][W+2][256], halo = 0
__global__ void conv_in_k(const float* __restrict__ x, unsigned short* __restrict__ dst,
                          int H, int total) {
  int idx = blockIdx.x * 256 + threadIdx.x;
  if (idx >= total) return;
  const int W = H, Hp = H + 2, Wp = H + 2;
  int c8 = idx & 31;
  int rest = idx >> 5;            // (n*Hp + yp)*Wp + xp
  int xp = rest % Wp;
  int r2 = rest / Wp;
  int yp = r2 % Hp;
  int n = r2 / Hp;
  u32x4 o = {0u, 0u, 0u, 0u};
  int iy = yp - 1, ix = xp - 1;
  if ((unsigned)iy < (unsigned)H && (unsigned)ix < (unsigned)W) {
    const float* s = x + ((long)((n * H + iy) * W + ix) * 256 + c8 * 8);
    float4 a = *(const float4*)s;
    float4 b = *(const float4*)(s + 4);
    o.x = f2bf(a.x) | ((unsigned)f2bf(a.y) << 16);
    o.y = f2bf(a.z) | ((unsigned)f2bf(a.w) << 16);
    o.z = f2bf(b.x) | ((unsigned)f2bf(b.y) << 16);
    o.w = f2bf(b.z) | ((unsigned)f2bf(b.w) << 16);
  }
  *(u32x4*)(dst + (long)idx * 8) = o;
}

// -------- HWIO fp32 -> bf16 MFMA-fragment layout
// chunk f: l=f&63; ks=(f>>6)&1; jg=(f>>7)%NB; stage=(f>>7)/NB  (stage = tap*4+cc)
// lane l holds B[col = jg*16 + (l&15)][k = stage*64 + ks*32 + (l>>4)*8 + 0..7]
__global__ void conv_w_k(const float* __restrict__ w, unsigned short* __restrict__ wTf,
                         int CoutReal, int NB, int totalChunks) {
  int f = blockIdx.x * 256 + threadIdx.x;
  if (f >= totalChunks) return;
  int l = f & 63;
  int t2 = f >> 6;
  int ks = t2 & 1;
  int t3 = t2 >> 1;
  int jg = t3 % NB;
  int stage = t3 / NB;
  int col = jg * 16 + (l & 15);
  int kbase = stage * 64 + ks * 32 + ((l >> 4) << 3);
  u32x4 o = {0u, 0u, 0u, 0u};
  if (col < CoutReal) {
    unsigned short v[8];
#pragma unroll
    for (int e = 0; e < 8; ++e)
      v[e] = f2bf(w[(long)(kbase + e) * CoutReal + col]);
    o.x = v[0] | ((unsigned)v[1] << 16);
    o.y = v[2] | ((unsigned)v[3] << 16);
    o.z = v[4] | ((unsigned)v[5] << 16);
    o.w = v[6] | ((unsigned)v[7] << 16);
  }
  *(u32x4*)(wTf + (long)f * 8) = o;
}

// ---------------------------------------------------------------- conv 3x3
// Implicit GEMM with halo-reuse A staging. Tile 128 px x 128 cout, 4 waves 1x4
// (each wave: all 128 px x 32 couts). A: LDS halo tile [NR][W+2][64ch] per
// cc-slice, staged once, swizzled (chunk ^= row&7 via pre-swizzled gload src).
// B: straight from L2 in MFMA-fragment layout (no LDS, no barriers).
template<bool FINAL>
__global__ __launch_bounds__(256, 3)
void conv3x3_k(const unsigned short* __restrict__ src,
               const unsigned short* __restrict__ wTf,
               const float* __restrict__ bias,
               unsigned short* __restrict__ dstAct,
               float* __restrict__ dstOut,
               int H, int lW, int lHW, int CoutReal, int NB, unsigned magicRL)
{
  __shared__ char smem[53248];              // A halo (<=416 rows x 128B); C-tile reuses [0,32K)
  const int tid = threadIdx.x;
  const int W = H, RL = W + 2, Hp = H + 2; // RL == Wp
  const int ROWS = 128 >> lW;               // output rows per 128-px tile
  const int NR = ROWS + 2;
  const int NROWS = NR * RL;                // LDS halo rows
  const int NITER = (NROWS * 8 + 255) >> 8; // 16B chunks / 256 threads
  const int tileM = blockIdx.x * 128;
  const int tileN = blockIdx.y * 128;
  const int n_img = tileM >> lHW;
  const int y0 = (tileM >> lW) & (H - 1);

  // per-thread staging source offsets (elements, cc=0); LDS dest stays linear,
  // source carries the inverse swizzle (chunk l = c ^ (r&7))
  int srcOff[13];
#pragma unroll
  for (int j = 0; j < 13; ++j) {
    if (j < NITER) {
      int q = j * 256 + tid;
      int r = q >> 3, c = q & 7;
      if (r >= NROWS) r = 0;                // tail chunks: harmless duplicate
      int ry = (int)(((unsigned long long)(unsigned)r * magicRL) >> 32);
      int ix = r - ry * RL;
      int lch = c ^ (r & 7);
      srcOff[j] = ((n_img * Hp + y0 + ry) * RL + ix) * 256 + lch * 8;
    } else {
      srcOff[j] = 0;
    }
  }

  const int lane = tid & 63;
  const int wv = tid >> 6;
  const int l15 = lane & 15;
  const int k8 = lane >> 4;
  int rBase[8];
#pragma unroll
  for (int m = 0; m < 8; ++m) {
    int pxt = m * 16 + l15;
    rBase[m] = ((pxt >> lW) * RL) + (pxt & (W - 1));
  }
  const long jgBase = (tileN >> 4) + wv * 2;

  f32x4 acc[8][2];
#pragma unroll
  for (int m = 0; m < 8; ++m)
#pragma unroll
    for (int n = 0; n < 2; ++n)
      acc[m][n] = (f32x4){0.f, 0.f, 0.f, 0.f};

  for (int cc = 0; cc < 4; ++cc) {
    if (cc) __syncthreads();                // all reads of previous slice done
#pragma unroll
    for (int j = 0; j < 13; ++j)
      if (j < NITER)
        gload16(src + srcOff[j] + cc * 64, smem + j * 4096 + tid * 16);
    __syncthreads();                        // vmcnt(0) drain before barrier
#pragma unroll
    for (int tap = 0; tap < 9; ++tap) {
      const int ky = tap / 3, kx = tap % 3;
      bf16x8 bv[2][2];
#pragma unroll
      for (int n = 0; n < 2; ++n)
#pragma unroll
        for (int ks = 0; ks < 2; ++ks) {
          const long fi = ((long)(tap * 4 + cc) * NB + jgBase + n) * 2 + ks;
          bv[n][ks] = *(const bf16x8*)(wTf + fi * 512 + lane * 8);
        }
#pragma unroll
      for (int m = 0; m < 8; ++m) {
        const int rA = rBase[m] + ky * RL + kx;
        const int a0 = rA * 128 + ((k8 ^ (rA & 7)) << 4);
        bf16x8 av0 = *(const bf16x8*)(smem + a0);
        bf16x8 av1 = *(const bf16x8*)(smem + (a0 ^ 64));
        acc[m][0] = __builtin_amdgcn_mfma_f32_16x16x32_bf16(av0, bv[0][0], acc[m][0], 0, 0, 0);
        acc[m][0] = __builtin_amdgcn_mfma_f32_16x16x32_bf16(av1, bv[0][1], acc[m][0], 0, 0, 0);
        acc[m][1] = __builtin_amdgcn_mfma_f32_16x16x32_bf16(av0, bv[1][0], acc[m][1], 0, 0, 0);
        acc[m][1] = __builtin_amdgcn_mfma_f32_16x16x32_bf16(av1, bv[1][1], acc[m][1], 0, 0, 0);
      }
    }
  }

  // epilogue: C/D layout col=lane&15, row=(lane>>4)*4+reg
  if (FINAL) {
#pragma unroll
    for (int n = 0; n < 2; ++n) {
      const int colG = tileN + wv * 32 + n * 16 + l15;
      if (colG < CoutReal) {
        const float bvl = bias[colG];
#pragma unroll
        for (int m = 0; m < 8; ++m)
#pragma unroll
          for (int r = 0; r < 4; ++r) {
            const int p = tileM + m * 16 + (k8 << 2) + r;
            dstOut[(long)p * CoutReal + colG] = acc[m][n][r] + bvl;
          }
      }
    }
  } else {
    __syncthreads();                        // done reading A LDS; reuse as C tile
    unsigned short* cl = (unsigned short*)smem;
#pragma unroll
    for (int n = 0; n < 2; ++n) {
      const int col = wv * 32 + n * 16 + l15;
      const float bvl = bias[tileN + col];
#pragma unroll
      for (int m = 0; m < 8; ++m)
#pragma unroll
        for (int r = 0; r < 4; ++r) {
          const int px = m * 16 + (k8 << 2) + r;
          const int cphys = ((col >> 3) + (px & 12)) & 15;   // bank swizzle
          cl[px * 128 + cphys * 8 + (col & 7)] = f2bf(fmaxf(acc[m][n][r] + bvl, 0.f));
        }
    }
    __syncthreads();
#pragma unroll
    for (int j = 0; j < 8; ++j) {
      const int chunk = j * 256 + tid;
      const int px = chunk >> 4, c = chunk & 15;
      const int cphys = (c + (px & 12)) & 15;
      u32x4 v = *(const u32x4*)(cl + px * 128 + cphys * 8);
      const int p = tileM + px;
      const int yi = (p >> lW) & (H - 1);
      const int xi = p & (W - 1);
      const long o = ((long)((p >> lHW) * Hp + yi + 1) * RL + xi + 1) * 256 + tileN + c * 8;
      *(u32x4*)(dstAct + o) = v;
    }
  }
}

// ---------------------------------------------------------------- host
static void run_branch(const unsigned short* A, unsigned short* Am, unsigned short* B,
                       const unsigned short* wT, const float* bias,
                       const unsigned short* wTout, const float* biasOut,
                       int CoutReal, int CoutPad, int NBf, float* out,
                       int H, int lW, int lHW, int M, unsigned magic, hipStream_t stream) {
  dim3 blk(256);
  dim3 g1(M / 128, 2);
  conv3x3_k<false><<<g1, blk, 0, stream>>>(A, wT + 0L * 589824, bias + 0, B, nullptr, H, lW, lHW, 256, 16, magic);
  conv3x3_k<false><<<g1, blk, 0, stream>>>(B, wT + 1L * 589824, bias + 256, Am, nullptr, H, lW, lHW, 256, 16, magic);
  conv3x3_k<false><<<g1, blk, 0, stream>>>(Am, wT + 2L * 589824, bias + 512, B, nullptr, H, lW, lHW, 256, 16, magic);
  conv3x3_k<false><<<g1, blk, 0, stream>>>(B, wT + 3L * 589824, bias + 768, Am, nullptr, H, lW, lHW, 256, 16, magic);
  dim3 g2(M / 128, CoutPad / 128);
  conv3x3_k<true><<<g2, blk, 0, stream>>>(Am, wTout, biasOut, nullptr, out, H, lW, lHW, CoutReal, NBf, magic);
}

extern "C" void kernel_launch(void* const* d_in, const int* in_sizes, int n_in,
                              void* d_out, int out_size, void* d_ws, size_t ws_size,
                              hipStream_t stream) {
  const float* x[3] = {(const float*)d_in[0], (const float*)d_in[1], (const float*)d_in[2]};
  const float* cls_w      = (const float*)d_in[3];
  const float* cls_b      = (const float*)d_in[4];
  const float* bbox_w     = (const float*)d_in[5];
  const float* bbox_b     = (const float*)d_in[6];
  const float* cls_out_w  = (const float*)d_in[7];
  const float* cls_out_b  = (const float*)d_in[8];
  const float* bbox_out_w = (const float*)d_in[9];
  const float* bbox_out_b = (const float*)d_in[10];
  float* out = (float*)d_out;

  char* ws = (char*)d_ws;
  unsigned short* bufA = (unsigned short*)ws;
  unsigned short* bufB = (unsigned short*)(ws + 69222400);
  unsigned short* wt   = (unsigned short*)(ws + 138444800);
  unsigned short* wT_cls      = wt;                       // 4 * 36*16*2*512
  unsigned short* wT_bbox     = wt + 4L * 589824;
  unsigned short* wT_cls_out  = wt + 8L * 589824;         // 36*48*2*512
  unsigned short* wT_bbox_out = wT_cls_out + 1769472;     // 36*8*2*512

  // ---- weight prep (fragment layout)
  for (int i = 0; i < 4; ++i) {
    conv_w_k<<<288, 256, 0, stream>>>(cls_w  + (long)i * 589824, wT_cls  + (long)i * 589824, 256, 16, 73728);
    conv_w_k<<<288, 256, 0, stream>>>(bbox_w + (long)i * 589824, wT_bbox + (long)i * 589824, 256, 16, 73728);
  }
  conv_w_k<<<864, 256, 0, stream>>>(cls_out_w,  wT_cls_out,  720, 48, 221184);
  conv_w_k<<<144, 256, 0, stream>>>(bbox_out_w, wT_bbox_out, 36, 8, 36864);

  const int  Hs[3]   = {128, 64, 32};
  const int  lWs[3]  = {7, 6, 5};
  const int  lHWs[3] = {14, 12, 10};
  const long clsOff[3] = {0L, 94371840L, 117964800L};
  const long boxOff[3] = {123863040L, 128581632L, 129761280L};

  for (int lv = 0; lv < 3; ++lv) {
    const int H = Hs[lv], Hp = H + 2;
    const int M = 8 * H * H;
    const int paddedElems = 8 * Hp * Hp * 256;
    const int totalConv = 8 * Hp * Hp * 32;
    const unsigned magic = (unsigned)((0x100000000ULL + (unsigned long long)(Hp) - 1) / (unsigned long long)Hp);

    // zero bufB (halo must be 0; interiors get overwritten by convs)
    zero_k<<<2048, 256, 0, stream>>>((u32x4*)bufB, paddedElems / 8);

    // cls branch
    conv_in_k<<<(totalConv + 255) / 256, 256, 0, stream>>>(x[lv], bufA, H, totalConv);
    run_branch(bufA, bufA, bufB, wT_cls, cls_b, wT_cls_out, cls_out_b,
               720, 768, 48, out + clsOff[lv], H, lWs[lv], lHWs[lv], M, magic, stream);

    // bbox branch (re-convert input; cls chain overwrote bufA interior, halo intact)
    conv_in_k<<<(totalConv + 255) / 256, 256, 0, stream>>>(x[lv], bufA, H, totalConv);
    run_branch(bufA, bufA, bufB, wT_bbox, bbox_b, wT_bbox_out, bbox_out_b,
               36, 128, 8, out + boxOff[lv], H, lWs[lv], lHWs[lv], M, magic, stream);
  }
}